// Round 1
// baseline (458.077 us; speedup 1.0000x reference)
//
#include <hip/hip_runtime.h>
#include <cstdint>
#include <cstddef>

#define BN 4
#define NN 100000
#define CC 41
#define NCLS 40
#define PROP 100
#define NEGV (-1e9f)
#define IOU_T 0.3f
#define SCORE_T 0.7f
#define MAXR 4.135166556742356f
#define NCHUNK 1563        // ceil(100000/64)
#define NCHUNK_PAD 1600    // 25*64
#define NBMP 3125          // ceil(100000/32)

__device__ __forceinline__ unsigned int encf(float x) {
  unsigned int u = __float_as_uint(x);
  return (u & 0x80000000u) ? ~u : (u | 0x80000000u);
}
__device__ __forceinline__ float decf(unsigned int e) {
  unsigned int u = (e & 0x80000000u) ? (e ^ 0x80000000u) : ~e;
  return __uint_as_float(u);
}

__device__ __forceinline__ float iou_f(float ax1, float ay1, float ax2, float ay2,
                                       float bx1, float by1, float bx2, float by2) {
  float ix1 = fmaxf(ax1, bx1), iy1 = fmaxf(ay1, by1);
  float ix2 = fminf(ax2, bx2), iy2 = fminf(ay2, by2);
  float inter = fmaxf(ix2 - ix1, 0.0f) * fmaxf(iy2 - iy1, 0.0f);
  float a1 = (ax2 - ax1) * (ay2 - ay1);
  float a2 = (bx2 - bx1) * (by2 - by1);
  return inter / fmaxf(a1 + a2 - inter, 1e-9f);
}

// ---------------- Kernel A: decode + clip boxes ----------------
__global__ void decode_kernel(const float4* __restrict__ regress,
                              const float4* __restrict__ anchors,
                              float4* __restrict__ boxes) {
  int i = blockIdx.x * 256 + threadIdx.x;
  if (i >= BN * NN) return;
  int n = i % NN;
  float4 d = regress[i];
  float4 a = anchors[n];
  float w = a.z - a.x, h = a.w - a.y;
  float cx = a.x + 0.5f * w, cy = a.y + 0.5f * h;
  float dx = d.x * 0.1f, dy = d.y * 0.1f;
  float dw = fminf(fmaxf(d.z * 0.2f, -MAXR), MAXR);
  float dh = fminf(fmaxf(d.w * 0.2f, -MAXR), MAXR);
  float pcx = cx + dx * w, pcy = cy + dy * h;
  float pw = w * expf(dw), ph = h * expf(dh);
  float4 o;
  o.x = fminf(fmaxf(pcx - 0.5f * pw, 0.0f), 1.0f);
  o.y = fminf(fmaxf(pcy - 0.5f * ph, 0.0f), 1.0f);
  o.z = fminf(fmaxf(pcx + 0.5f * pw, 0.0f), 1.0f);
  o.w = fminf(fmaxf(pcy + 0.5f * ph, 0.0f), 1.0f);
  boxes[i] = o;
}

// ---------------- Kernel B: masked scores + per-chunk maxima ----------------
__global__ void score_kernel(const float* __restrict__ logits,
                             float* __restrict__ s0,
                             float* __restrict__ cmaxg) {
  __shared__ float lg[256 * CC];  // 42 KB
  int b = blockIdx.y;
  int n0 = blockIdx.x * 256;
  int tid = threadIdx.x;
  int rows = NN - n0; if (rows > 256) rows = 256;
  int total4 = rows * CC / 4;  // rows is a multiple of 4 always
  const float4* src = (const float4*)(logits + ((size_t)b * NN + n0) * CC);
  float4* dst = (float4*)lg;
  for (int i = tid; i < total4; i += 256) dst[i] = src[i];
  __syncthreads();

  bool act = tid < rows;
  int n = n0 + tid;
  float bestv = 0.0f; int bestc = 0;
  if (act) {
    bestv = lg[tid * CC];
    #pragma unroll
    for (int c = 1; c < CC; ++c) {
      float v = lg[tid * CC + c];
      if (v > bestv) { bestv = v; bestc = c; }
    }
  }
  bool fg = act && (bestc > 0);
  int lane = tid & 63;
  int chunk = (n0 >> 6) + (tid >> 6);

  for (int c = 1; c < CC; ++c) {
    float v = act ? lg[tid * CC + c] : NEGV;
    float s = (fg && v >= SCORE_T) ? v : NEGV;
    size_t prob = (size_t)(b * NCLS + (c - 1));
    if (act) s0[prob * NN + n] = s;
    float m = s;
    #pragma unroll
    for (int off = 32; off; off >>= 1) m = fmaxf(m, __shfl_xor(m, off));
    if (lane == 0 && chunk < NCHUNK) cmaxg[prob * NCHUNK + chunk] = m;
  }
}

// ---------------- Kernel C: exact greedy NMS, one wave per (b, class) ----------------
__launch_bounds__(64)
__global__ void nms_kernel(const float* __restrict__ s0,
                           const float4* __restrict__ boxes,
                           const float* __restrict__ cmaxg,
                           int* __restrict__ oidx,
                           float* __restrict__ osc) {
  int prob = blockIdx.x;            // b*40 + c
  int b = prob / NCLS;
  int lane = threadIdx.x;
  __shared__ unsigned int cmax[NCHUNK_PAD];
  __shared__ unsigned int removed[NBMP];
  __shared__ float selx1[PROP], sely1[PROP], selx2[PROP], sely2[PROP];

  for (int i = lane; i < NBMP; i += 64) removed[i] = 0u;
  const float* s0p = s0 + (size_t)prob * NN;
  for (int i = lane; i < NCHUNK_PAD; i += 64)
    cmax[i] = (i < NCHUNK) ? encf(cmaxg[(size_t)prob * NCHUNK + i]) : 0u;
  __syncthreads();

  const unsigned int ENEG = encf(NEGV);
  int nsel = 0;

  for (int it = 0; it < NN + PROP; ++it) {
    // (A) best chunk: per-lane scan (strict > keeps lowest chunk idx), then u64 butterfly
    unsigned int be = 0u; int bi = 0;
    #pragma unroll
    for (int r = 0; r < NCHUNK_PAD / 64; ++r) {
      int i = lane + (r << 6);
      unsigned int e = cmax[i];
      if (e > be) { be = e; bi = i; }
    }
    unsigned long long bk = ((unsigned long long)be << 32) | (unsigned int)(~bi);
    #pragma unroll
    for (int off = 32; off; off >>= 1) {
      unsigned long long o = __shfl_xor(bk, off);
      if (o > bk) bk = o;
    }
    if ((unsigned int)(bk >> 32) <= ENEG) break;   // exhausted
    int j = (int)(~(unsigned int)bk);

    // (B) rescan chunk j (coalesced), prefetch candidate boxes alongside
    int n = (j << 6) + lane;
    float s = NEGV;
    float4 bx = make_float4(0.0f, 0.0f, 0.0f, 0.0f);
    if (n < NN) {
      bx = boxes[(size_t)b * NN + n];
      if (!((removed[n >> 5] >> (n & 31)) & 1u)) s = s0p[n];
    }
    unsigned long long k2 = ((unsigned long long)encf(s) << 32) | (unsigned int)(~n);
    #pragma unroll
    for (int off = 32; off; off >>= 1) {
      unsigned long long o = __shfl_xor(k2, off);
      if (o > k2) k2 = o;
    }
    int nstar = (int)(~(unsigned int)k2);
    int wl = nstar & 63;
    float wx1 = __shfl(bx.x, wl), wy1 = __shfl(bx.y, wl);
    float wx2 = __shfl(bx.z, wl), wy2 = __shfl(bx.w, wl);

    // (C) suppression check vs selected list (lazy NMS == reference greedy NMS)
    bool over = false;
    if (lane < nsel)
      over = iou_f(wx1, wy1, wx2, wy2, selx1[lane], sely1[lane], selx2[lane], sely2[lane]) > IOU_T;
    if (lane + 64 < nsel)
      over = over || (iou_f(wx1, wy1, wx2, wy2,
                            selx1[lane + 64], sely1[lane + 64],
                            selx2[lane + 64], sely2[lane + 64]) > IOU_T);
    bool supp = __any(over);

    // (D) remove winner, refresh chunk max (u32 reduce, index not needed)
    if (lane == wl) removed[nstar >> 5] |= (1u << (nstar & 31));
    unsigned int e2 = (lane == wl) ? ENEG : encf(s);
    #pragma unroll
    for (int off = 32; off; off >>= 1) {
      unsigned int o = __shfl_xor(e2, off);
      if (o > e2) e2 = o;
    }
    if (lane == 0) cmax[j] = e2;

    if (!supp) {
      if (lane == wl) {
        oidx[prob * PROP + nsel] = nstar;
        osc [prob * PROP + nsel] = s;
        selx1[nsel] = bx.x; sely1[nsel] = bx.y;
        selx2[nsel] = bx.z; sely2[nsel] = bx.w;
      }
      nsel++;
      if (nsel == PROP) break;
    }
    __syncthreads();
  }

  __syncthreads();
  for (int p = nsel + lane; p < PROP; p += 64) {
    oidx[prob * PROP + p] = -1;
    osc [prob * PROP + p] = NEGV;
  }
}

// ---------------- Kernel D: per-batch top-100 of 4000 (bitonic) + gather ----------------
__global__ void topk_kernel(const float* __restrict__ logits,
                            const float4* __restrict__ boxes,
                            const int* __restrict__ oidx,
                            const float* __restrict__ osc,
                            float* __restrict__ out) {
  __shared__ unsigned long long keys[4096];  // 32 KB
  int b = blockIdx.x;
  int tid = threadIdx.x;
  for (int i = tid; i < 4096; i += 256) {
    unsigned long long key = 0ull;
    if (i < NCLS * PROP) {
      float sc = osc[b * NCLS * PROP + i];
      key = ((unsigned long long)encf(sc) << 32) | (unsigned int)(~i);
    }
    keys[i] = ~key;  // ascending sort of ~key == descending sort of key, ties -> lower i
  }
  __syncthreads();
  for (int k = 2; k <= 4096; k <<= 1) {
    for (int j = k >> 1; j > 0; j >>= 1) {
      for (int t = tid; t < 4096; t += 256) {
        int ixj = t ^ j;
        if (ixj > t) {
          unsigned long long a = keys[t], c2 = keys[ixj];
          bool up = ((t & k) == 0);
          if ((a > c2) == up) { keys[t] = c2; keys[ixj] = a; }
        }
      }
      __syncthreads();
    }
  }
  if (tid < PROP) {
    unsigned long long key = ~keys[tid];
    unsigned int e = (unsigned int)(key >> 32);
    float sc = decf(e);
    bool ok = sc > 0.5f * NEGV;
    int kk = (int)(~(unsigned int)key);
    if (kk < 0 || kk >= NCLS * PROP) kk = 0;
    int idx = ok ? oidx[b * NCLS * PROP + kk] : 0;
    if (idx < 0) idx = 0;
    float m = ok ? 1.0f : 0.0f;
    const float* lp = logits + ((size_t)b * NN + idx) * CC;
    float* outl = out + ((size_t)b * PROP + tid) * CC;
    #pragma unroll
    for (int c = 0; c < CC; ++c) outl[c] = lp[c] * m;
    float4 bb = boxes[(size_t)b * NN + idx];
    float* outb = out + (size_t)BN * PROP * CC + ((size_t)b * PROP + tid) * 4;
    outb[0] = bb.x * m; outb[1] = bb.y * m; outb[2] = bb.z * m; outb[3] = bb.w * m;
  }
}

extern "C" void kernel_launch(void* const* d_in, const int* in_sizes, int n_in,
                              void* d_out, int out_size, void* d_ws, size_t ws_size,
                              hipStream_t stream) {
  const float* logits  = (const float*)d_in[0];  // (4,100000,41)
  const float* regress = (const float*)d_in[1];  // (4,100000,4)
  const float* anchors = (const float*)d_in[2];  // (100000,4)
  float* out = (float*)d_out;

  float* boxes = (float*)d_ws;                                   // 1,600,000 f
  float* s0    = boxes + (size_t)BN * NN * 4;                    // 16,000,000 f
  float* cmaxg = s0 + (size_t)BN * NCLS * NN;                    // 250,080 f
  float* osc   = cmaxg + (size_t)BN * NCLS * NCHUNK;             // 16,000 f
  int*   oidx  = (int*)(osc + (size_t)BN * NCLS * PROP);         // 16,000 i32

  decode_kernel<<<(BN * NN + 255) / 256, 256, 0, stream>>>(
      (const float4*)regress, (const float4*)anchors, (float4*)boxes);
  score_kernel<<<dim3((NN + 255) / 256, BN), 256, 0, stream>>>(logits, s0, cmaxg);
  nms_kernel<<<BN * NCLS, 64, 0, stream>>>(s0, (const float4*)boxes, cmaxg, oidx, osc);
  topk_kernel<<<BN, 256, 0, stream>>>(logits, (const float4*)boxes, oidx, osc, out);
}

// Round 2
// 409.185 us; speedup vs baseline: 1.1195x; 1.1195x over previous
//
#include <hip/hip_runtime.h>
#include <cstdint>
#include <cstddef>

#define BN 4
#define NN 100000
#define CC 41
#define NCLS 40
#define PROP 100
#define NEGV (-1e9f)
#define IOU_T 0.3f
#define SCORE_T 0.7f
#define MAXR 4.135166556742356f
#define CAP 2048
#define TARGET 768
#define NBIN 256
#define BINSCL (256.0f / 5.3f)

__device__ __forceinline__ unsigned int encf(float x) {
  unsigned int u = __float_as_uint(x);
  return (u & 0x80000000u) ? ~u : (u | 0x80000000u);
}
__device__ __forceinline__ float decf(unsigned int e) {
  unsigned int u = (e & 0x80000000u) ? (e ^ 0x80000000u) : ~e;
  return __uint_as_float(u);
}
__device__ __forceinline__ int binof(float s) {
  int b = (int)((s - SCORE_T) * BINSCL);
  return b > 255 ? 255 : b;
}

__device__ __forceinline__ float iou_f(float ax1, float ay1, float ax2, float ay2,
                                       float bx1, float by1, float bx2, float by2) {
  float ix1 = fmaxf(ax1, bx1), iy1 = fmaxf(ay1, by1);
  float ix2 = fminf(ax2, bx2), iy2 = fminf(ay2, by2);
  float inter = fmaxf(ix2 - ix1, 0.0f) * fmaxf(iy2 - iy1, 0.0f);
  float a1 = (ax2 - ax1) * (ay2 - ay1);
  float a2 = (bx2 - bx1) * (by2 - by1);
  return inter / fmaxf(a1 + a2 - inter, 1e-9f);
}

// ---------------- Kernel A: decode + clip boxes ----------------
__global__ void decode_kernel(const float4* __restrict__ regress,
                              const float4* __restrict__ anchors,
                              float4* __restrict__ boxes) {
  int i = blockIdx.x * 256 + threadIdx.x;
  if (i >= BN * NN) return;
  int n = i % NN;
  float4 d = regress[i];
  float4 a = anchors[n];
  float w = a.z - a.x, h = a.w - a.y;
  float cx = a.x + 0.5f * w, cy = a.y + 0.5f * h;
  float dx = d.x * 0.1f, dy = d.y * 0.1f;
  float dw = fminf(fmaxf(d.z * 0.2f, -MAXR), MAXR);
  float dh = fminf(fmaxf(d.w * 0.2f, -MAXR), MAXR);
  float pcx = cx + dx * w, pcy = cy + dy * h;
  float pw = w * expf(dw), ph = h * expf(dh);
  float4 o;
  o.x = fminf(fmaxf(pcx - 0.5f * pw, 0.0f), 1.0f);
  o.y = fminf(fmaxf(pcy - 0.5f * ph, 0.0f), 1.0f);
  o.z = fminf(fmaxf(pcx + 0.5f * pw, 0.0f), 1.0f);
  o.w = fminf(fmaxf(pcy + 0.5f * ph, 0.0f), 1.0f);
  boxes[i] = o;
}

// ---------------- Kernel B: masked dense scores ----------------
__global__ void score_kernel(const float* __restrict__ logits,
                             float* __restrict__ s0) {
  __shared__ float lg[256 * CC];  // 42 KB
  int b = blockIdx.y;
  int n0 = blockIdx.x * 256;
  int tid = threadIdx.x;
  int rows = NN - n0; if (rows > 256) rows = 256;
  int total4 = rows * CC / 4;
  const float4* src = (const float4*)(logits + ((size_t)b * NN + n0) * CC);
  float4* dst = (float4*)lg;
  for (int i = tid; i < total4; i += 256) dst[i] = src[i];
  __syncthreads();

  bool act = tid < rows;
  int n = n0 + tid;
  float bestv = 0.0f; int bestc = 0;
  if (act) {
    bestv = lg[tid * CC];
    #pragma unroll
    for (int c = 1; c < CC; ++c) {
      float v = lg[tid * CC + c];
      if (v > bestv) { bestv = v; bestc = c; }
    }
  }
  bool fg = act && (bestc > 0);
  if (!act) return;
  for (int c = 1; c < CC; ++c) {
    float v = lg[tid * CC + c];
    float s = (fg && v >= SCORE_T) ? v : NEGV;
    size_t prob = (size_t)(b * NCLS + (c - 1));
    s0[prob * NN + n] = s;
  }
}

// ---------------- Kernel C: sorted-walk greedy NMS, one block per (b, class) ----------------
__launch_bounds__(256)
__global__ void nms_kernel(const float* __restrict__ s0,
                           const float4* __restrict__ boxes,
                           int* __restrict__ oidx,
                           float* __restrict__ osc) {
  __shared__ unsigned int hist[NBIN];
  __shared__ unsigned long long keysL[CAP];   // 16 KB
  __shared__ float4 boxesL[CAP];              // 32 KB
  __shared__ float4 selL[PROP];
  __shared__ int sh_cnt, sh_lo, sh_nsel;
  __shared__ unsigned int sh_cum;

  int prob = blockIdx.x;            // b*40 + c
  int b = prob / NCLS;
  int tid = threadIdx.x;

  hist[tid] = 0u;  // blockDim == 256 == NBIN
  __syncthreads();

  const float4* s4 = (const float4*)(s0 + (size_t)prob * NN);
  const float4* bx4 = boxes + (size_t)b * NN;

  // pass A: histogram of eligible scores
  for (int i = tid; i < NN / 4; i += 256) {
    float4 v = s4[i];
    if (v.x >= SCORE_T) atomicAdd(&hist[binof(v.x)], 1u);
    if (v.y >= SCORE_T) atomicAdd(&hist[binof(v.y)], 1u);
    if (v.z >= SCORE_T) atomicAdd(&hist[binof(v.z)], 1u);
    if (v.w >= SCORE_T) atomicAdd(&hist[binof(v.w)], 1u);
  }
  __syncthreads();

  int hibin = NBIN;
  int nsel = 0;

  while (true) {
    // window selection on thread 0
    if (tid == 0) {
      int lo = hibin; unsigned int cum = 0;
      while (lo > 0) {
        unsigned int nb = hist[lo - 1];
        if (cum + nb > CAP && cum > 0) break;
        cum += nb; lo--;
        if (cum >= TARGET) break;
      }
      sh_lo = lo; sh_cum = cum; sh_cnt = 0;
    }
    __syncthreads();
    int lo = sh_lo;
    unsigned int expect = sh_cum;
    if (expect == 0) break;

    // pass B: compact candidates in bin-window [lo, hibin)
    for (int i = tid; i < NN / 4; i += 256) {
      float4 v = s4[i];
      float sv[4] = {v.x, v.y, v.z, v.w};
      #pragma unroll
      for (int j = 0; j < 4; ++j) {
        float s = sv[j];
        if (s >= SCORE_T) {
          int bn = binof(s);
          if (bn >= lo && bn < hibin) {
            int slot = atomicAdd(&sh_cnt, 1);
            if (slot < CAP) {
              int idx = 4 * i + j;
              keysL[slot] = ((unsigned long long)encf(s) << 32)
                          | ((unsigned long long)((131071 - idx) & 0x1FFFF) << 15)
                          | (unsigned long long)slot;
              boxesL[slot] = bx4[idx];
            }
          }
        }
      }
    }
    __syncthreads();
    int ncand = sh_cnt < CAP ? sh_cnt : CAP;

    // pad to pow2 and bitonic sort descending
    int M = 64; while (M < ncand) M <<= 1;
    for (int i = ncand + tid; i < M; i += 256) keysL[i] = 0ull;
    __syncthreads();
    for (int k = 2; k <= M; k <<= 1) {
      for (int j = k >> 1; j > 0; j >>= 1) {
        for (int t = tid; t < M; t += 256) {
          int ixj = t ^ j;
          if (ixj > t) {
            unsigned long long a = keysL[t], c2 = keysL[ixj];
            bool up = ((t & k) == 0);       // up-region: descending
            if (up ? (a < c2) : (a > c2)) { keysL[t] = c2; keysL[ixj] = a; }
          }
        }
        __syncthreads();
      }
    }

    // walk: wave 0 only
    if (tid < 64) {
      int lane = tid;
      int ns = nsel;
      for (int base = 0; base < ncand && ns < PROP; base += 64) {
        int i = base + lane;
        bool valid = i < ncand;
        unsigned long long key = valid ? keysL[i] : 0ull;
        int slot = (int)(key & 0x7FFF);
        float4 bx = boxesL[valid ? slot : 0];
        float sc = decf((unsigned int)(key >> 32));
        int aidx = 131071 - (int)((key >> 15) & 0x1FFFF);
        bool supp = false;
        for (int j = 0; j < ns; ++j) {
          float4 sb = selL[j];
          supp = supp || (iou_f(bx.x, bx.y, bx.z, bx.w, sb.x, sb.y, sb.z, sb.w) > IOU_T);
        }
        unsigned long long live = __ballot(valid && !supp);
        while (live && ns < PROP) {
          int k = __ffsll(live) - 1;
          float x1 = __shfl(bx.x, k), y1 = __shfl(bx.y, k);
          float x2 = __shfl(bx.z, k), y2 = __shfl(bx.w, k);
          float ksc = __shfl(sc, k);
          int kidx = __shfl(aidx, k);
          if (lane == 0) {
            oidx[prob * PROP + ns] = kidx;
            osc [prob * PROP + ns] = ksc;
            selL[ns] = make_float4(x1, y1, x2, y2);
          }
          ns++;
          if (lane > k && valid && !supp)
            supp = iou_f(bx.x, bx.y, bx.z, bx.w, x1, y1, x2, y2) > IOU_T;
          live = __ballot(valid && !supp) & ~((2ull << k) - 1ull);
        }
      }
      if (lane == 0) sh_nsel = ns;
    }
    __syncthreads();
    nsel = sh_nsel;
    hibin = lo;
    if (nsel >= PROP || hibin == 0) break;
    __syncthreads();
  }

  // pad remaining outputs
  for (int p = nsel + tid; p < PROP; p += 256) {
    oidx[prob * PROP + p] = -1;
    osc [prob * PROP + p] = NEGV;
  }
}

// ---------------- Kernel D: per-batch top-100 of 4000 (bitonic) + gather ----------------
__global__ void topk_kernel(const float* __restrict__ logits,
                            const float4* __restrict__ boxes,
                            const int* __restrict__ oidx,
                            const float* __restrict__ osc,
                            float* __restrict__ out) {
  __shared__ unsigned long long keys[4096];  // 32 KB
  int b = blockIdx.x;
  int tid = threadIdx.x;
  for (int i = tid; i < 4096; i += 256) {
    unsigned long long key = 0ull;
    if (i < NCLS * PROP) {
      float sc = osc[b * NCLS * PROP + i];
      key = ((unsigned long long)encf(sc) << 32) | (unsigned int)(~i);
    }
    keys[i] = ~key;  // ascending sort of ~key == descending by (score, then lower i)
  }
  __syncthreads();
  for (int k = 2; k <= 4096; k <<= 1) {
    for (int j = k >> 1; j > 0; j >>= 1) {
      for (int t = tid; t < 4096; t += 256) {
        int ixj = t ^ j;
        if (ixj > t) {
          unsigned long long a = keys[t], c2 = keys[ixj];
          bool up = ((t & k) == 0);
          if ((a > c2) == up) { keys[t] = c2; keys[ixj] = a; }
        }
      }
      __syncthreads();
    }
  }
  if (tid < PROP) {
    unsigned long long key = ~keys[tid];
    unsigned int e = (unsigned int)(key >> 32);
    float sc = decf(e);
    bool ok = sc > 0.5f * NEGV;
    int kk = (int)(~(unsigned int)key);
    if (kk < 0 || kk >= NCLS * PROP) kk = 0;
    int idx = ok ? oidx[b * NCLS * PROP + kk] : 0;
    if (idx < 0) idx = 0;
    float m = ok ? 1.0f : 0.0f;
    const float* lp = logits + ((size_t)b * NN + idx) * CC;
    float* outl = out + ((size_t)b * PROP + tid) * CC;
    #pragma unroll
    for (int c = 0; c < CC; ++c) outl[c] = lp[c] * m;
    float4 bb = boxes[(size_t)b * NN + idx];
    float* outb = out + (size_t)BN * PROP * CC + ((size_t)b * PROP + tid) * 4;
    outb[0] = bb.x * m; outb[1] = bb.y * m; outb[2] = bb.z * m; outb[3] = bb.w * m;
  }
}

extern "C" void kernel_launch(void* const* d_in, const int* in_sizes, int n_in,
                              void* d_out, int out_size, void* d_ws, size_t ws_size,
                              hipStream_t stream) {
  const float* logits  = (const float*)d_in[0];  // (4,100000,41)
  const float* regress = (const float*)d_in[1];  // (4,100000,4)
  const float* anchors = (const float*)d_in[2];  // (100000,4)
  float* out = (float*)d_out;

  float* boxes = (float*)d_ws;                                   // 1,600,000 f
  float* s0    = boxes + (size_t)BN * NN * 4;                    // 16,000,000 f
  float* osc   = s0 + (size_t)BN * NCLS * NN;                    // 16,000 f
  int*   oidx  = (int*)(osc + (size_t)BN * NCLS * PROP);         // 16,000 i32

  decode_kernel<<<(BN * NN + 255) / 256, 256, 0, stream>>>(
      (const float4*)regress, (const float4*)anchors, (float4*)boxes);
  score_kernel<<<dim3((NN + 255) / 256, BN), 256, 0, stream>>>(logits, s0);
  nms_kernel<<<BN * NCLS, 256, 0, stream>>>(s0, (const float4*)boxes, oidx, osc);
  topk_kernel<<<BN, 256, 0, stream>>>(logits, (const float4*)boxes, oidx, osc, out);
}